// Round 3
// baseline (777.524 us; speedup 1.0000x reference)
//
#include <hip/hip_runtime.h>

typedef short short8 __attribute__((ext_vector_type(8)));
typedef float f32x4 __attribute__((ext_vector_type(4)));
typedef unsigned int uint2v __attribute__((ext_vector_type(2)));
typedef unsigned int uint4v __attribute__((ext_vector_type(4)));

constexpr int Hdim = 128;   // H
constexpr int Steps = 27;   // COL + ROW - 1
constexpr int Kdim = 384;   // 3H
constexpr int Ndim = 768;   // 6H
constexpr int ASTR = 392;   // A-row stride in shorts (784 B)
constexpr int GSTR = 193;   // g_lds row stride in floats (odd -> conflict-free)
constexpr int NGROUP = 128; // (cls, bn) pairs

__device__ __forceinline__ short f2bf(float f) {
  unsigned u = __float_as_uint(f);
  u += 0x7FFFu + ((u >> 16) & 1u);  // RNE
  return (short)(u >> 16);
}
__device__ __forceinline__ float bf2f(short s) {
  return __uint_as_float(((unsigned)(unsigned short)s) << 16);
}
__device__ __forceinline__ unsigned packbf(float v) {
  unsigned short hi = (unsigned short)f2bf(v);
  unsigned short lo = (unsigned short)f2bf(v - bf2f((short)hi));
  return ((unsigned)hi << 16) | (unsigned)lo;
}
__device__ __forceinline__ float sigmoidf_(float x) { return 1.0f / (1.0f + __expf(-x)); }
__device__ __forceinline__ float tanh_(float x) { return 1.0f - 2.0f / (__expf(2.0f * x) + 1.0f); }

#define ATOMIC_LD_RLX(p) __hip_atomic_load((p), __ATOMIC_RELAXED, __HIP_MEMORY_SCOPE_AGENT)
#define ATOMIC_LD_ACQ(p) __hip_atomic_load((p), __ATOMIC_ACQUIRE, __HIP_MEMORY_SCOPE_AGENT)
#define ATOMIC_ADD_REL(p, v) __hip_atomic_fetch_add((p), (v), __ATOMIC_RELEASE, __HIP_MEMORY_SCOPE_AGENT)

// ---- kernel 1: W_enc (fp32) -> MFMA B-fragment bf16, with output-column permutation ----
// permuted col p = q*192 + gate*32 + dl  <->  original n = gate*128 + q*32 + dl
// idx = ((cls*48 + pt)*12 + ks)*512 + lane*8 + j ; holds W[n(pt*16+(lane&15))][ks*32+(lane>>4)*8+j]
__global__ void prep_w(const float* __restrict__ W_enc, short* __restrict__ wfrag) {
  int idx = blockIdx.x * 256 + threadIdx.x;
  if (idx >= 2 * 48 * 12 * 512) return;
  int j = idx & 7;
  int lane = (idx >> 3) & 63;
  int rest = idx >> 9;
  int ks = rest % 12;
  int tmp = rest / 12;
  int pt = tmp % 48;
  int cls = tmp / 48;
  int p = pt * 16 + (lane & 15);
  int q = p / 192, c_loc = p % 192;
  int gate = c_loc >> 5, dl = c_loc & 31;
  int n = gate * 128 + q * 32 + dl;
  int k = ks * 32 + (lane >> 4) * 8 + j;
  wfrag[idx] = f2bf(W_enc[(cls * Ndim + n) * Kdim + k]);
}

// ---- kernel 2: front-end MLP, LDS-staged weights, 16 rows/block ----
constexpr int WBS = 66;  // wbuf stride (floats)
__global__ __launch_bounds__(128) void frontend16(
    const float* __restrict__ x, const float* __restrict__ fc3_w, const float* __restrict__ fc3_b,
    const float* __restrict__ fc4_w, const float* __restrict__ fc4_b,
    short* __restrict__ hg_hi, short* __restrict__ hg_lo) {
  const int t = threadIdx.x;
  const int row0 = blockIdx.x * 16;
  __shared__ float wbuf[128 * WBS];
  __shared__ float xs[16][64];
  __shared__ float h1[16][128];
  for (int f = t; f < 1024; f += 128) {
    int r = f >> 6, c = f & 63;
    xs[r][c] = x[(size_t)(row0 + r) * 64 + c];
  }
  for (int f = t; f < 8192; f += 128) {  // w3: [h][c]
    int h = f >> 6, c = f & 63;
    wbuf[h * WBS + c] = fc3_w[f];
  }
  const float b3 = fc3_b[t], b4 = fc4_b[t];
  __syncthreads();
  float a[16];
#pragma unroll
  for (int r = 0; r < 16; ++r) a[r] = b3;
#pragma unroll 4
  for (int c = 0; c < 64; c += 2) {
    float2 w = *(const float2*)&wbuf[t * WBS + c];
#pragma unroll
    for (int r = 0; r < 16; ++r) {
      float2 xv = *(const float2*)&xs[r][c];
      a[r] = fmaf(xv.x, w.x, a[r]);
      a[r] = fmaf(xv.y, w.y, a[r]);
    }
  }
  __syncthreads();  // done reading wbuf(w3) before restage
#pragma unroll
  for (int r = 0; r < 16; ++r) h1[r][t] = fmaxf(a[r], 0.f);
  float o[16];
#pragma unroll
  for (int r = 0; r < 16; ++r) o[r] = b4;
  for (int half = 0; half < 2; ++half) {
    for (int f = t; f < 8192; f += 128) {  // w4 half: [h][j0..63]
      int h = f >> 6, j = f & 63;
      wbuf[h * WBS + j] = fc4_w[h * 128 + half * 64 + j];
    }
    __syncthreads();
#pragma unroll 4
    for (int j = 0; j < 64; j += 2) {
      float2 w = *(const float2*)&wbuf[t * WBS + j];
#pragma unroll
      for (int r = 0; r < 16; ++r) {
        float2 hv = *(const float2*)&h1[r][half * 64 + j];
        o[r] = fmaf(hv.x, w.x, o[r]);
        o[r] = fmaf(hv.y, w.y, o[r]);
      }
    }
    __syncthreads();  // done reading this half before restage
  }
#pragma unroll
  for (int r = 0; r < 16; ++r) {
    short hb = f2bf(o[r]);
    hg_hi[(size_t)(row0 + r) * 128 + t] = hb;
    hg_lo[(size_t)(row0 + r) * 128 + t] = f2bf(o[r] - bf2f(hb));
  }
}

// ---- kernel 3: 4-wg groups; register weights; h-slab exchange via LLC + acq/rel flags ----
__global__ __launch_bounds__(256, 2) void witran(
    const short* __restrict__ hg_hi, const short* __restrict__ hg_lo,
    const short* __restrict__ wfrag, const float* __restrict__ B_enc,
    const float* __restrict__ fc1_w, const float* __restrict__ fc1_b,
    const float* __restrict__ fc2_w, const float* __restrict__ fc2_b,
    uint2v* __restrict__ pub, unsigned* __restrict__ flags, float* __restrict__ out) {
  const int wgq = blockIdx.x >> 7;    // 0..3 : owns gate dims [wgq*32, wgq*32+32)
  const int group = blockIdx.x & 127; // (cls, bn)
  const int cls = group & 1;
  const int bn = group >> 1;
  const int t = threadIdx.x;
  const int lane = t & 63;
  const int wv = t >> 6;
  const int arow = lane & 15;
  const int quad = lane >> 4;

  __shared__ __attribute__((aligned(16))) short Ahi[16 * ASTR];
  __shared__ __attribute__((aligned(16))) short Alo[16 * ASTR];
  __shared__ float g_lds[12 * GSTR];
  __shared__ float bias_l[192];
  __shared__ float red[128];

  for (int i = t; i < 16 * ASTR; i += 256) { Ahi[i] = 0; Alo[i] = 0; }
  if (t < 192) {  // bias for own slab: c_loc = gate*32+dl -> n = gate*128 + wgq*32 + dl
    int gate = t >> 5, dl = t & 31;
    bias_l[t] = B_enc[cls * Ndim + gate * 128 + wgq * 32 + dl];
  }

  // persistent weight fragments: wave wv owns pt = wgq*12 + wv*3 + {0,1,2}
  short8 w0[12], w1[12], w2[12];
  {
    const short* wfc = wfrag + (size_t)cls * (48 * 12 * 512) + (size_t)lane * 8;
    const int ptb = wgq * 12 + wv * 3;
#pragma unroll
    for (int ks = 0; ks < 12; ++ks) w0[ks] = *(const short8*)(wfc + ((ptb + 0) * 12 + ks) * 512);
#pragma unroll
    for (int ks = 0; ks < 12; ++ks) w1[ks] = *(const short8*)(wfc + ((ptb + 1) * 12 + ks) * 512);
#pragma unroll
    for (int ks = 0; ks < 12; ++ks) w2[ks] = *(const short8*)(wfc + ((ptb + 2) * 12 + ks) * 512);
  }

  const short* hgh = hg_hi + (size_t)bn * 192 * Hdim;
  const short* hgl = hg_lo + (size_t)bn * 192 * Hdim;
  unsigned* flag = flags + group * 16;  // 64 B padded
  unsigned acq_sink = 0;

  __syncthreads();

  // x segment for step 0
  if (t < 192) {
    int c = t >> 4, j8 = (t & 15) * 8;
    short8 vh = {0, 0, 0, 0, 0, 0, 0, 0}, vl = vh;
    if (c == 0) {
      vh = *(const short8*)(hgh + j8);
      vl = *(const short8*)(hgl + j8);
    }
    *(short8*)&Ahi[c * ASTR + 256 + j8] = vh;
    *(short8*)&Alo[c * ASTR + 256 + j8] = vl;
  }
  __syncthreads();

  const int abase = arow * ASTR + quad * 8;

  for (int s = 0; s < Steps; ++s) {
    // ---- (1) GEMM: A (LDS) x W (regs) -> own 192-col stripe ----
    f32x4 a0 = {0.f, 0.f, 0.f, 0.f}, a1 = a0, a2 = a0;
#pragma unroll
    for (int ks = 0; ks < 12; ++ks) {
      short8 ah = *(const short8*)&Ahi[abase + ks * 32];
      short8 al = *(const short8*)&Alo[abase + ks * 32];
      a0 = __builtin_amdgcn_mfma_f32_16x16x32_bf16(ah, w0[ks], a0, 0, 0, 0);
      a1 = __builtin_amdgcn_mfma_f32_16x16x32_bf16(ah, w1[ks], a1, 0, 0, 0);
      a2 = __builtin_amdgcn_mfma_f32_16x16x32_bf16(ah, w2[ks], a2, 0, 0, 0);
      a0 = __builtin_amdgcn_mfma_f32_16x16x32_bf16(al, w0[ks], a0, 0, 0, 0);
      a1 = __builtin_amdgcn_mfma_f32_16x16x32_bf16(al, w1[ks], a1, 0, 0, 0);
      a2 = __builtin_amdgcn_mfma_f32_16x16x32_bf16(al, w2[ks], a2, 0, 0, 0);
    }
    // ---- (2) spill D to LDS (local cols c_loc = wv*48 + nt*16 + arow) ----
    if (quad < 3) {
      int c0 = wv * 48 + arow;
#pragma unroll
      for (int r = 0; r < 4; ++r) {
        int row = quad * 4 + r;
        g_lds[row * GSTR + c0 + 0] = a0[r];
        g_lds[row * GSTR + c0 + 16] = a1[r];
        g_lds[row * GSTR + c0 + 32] = a2[r];
      }
    }
    __syncthreads();

    // ---- (3) gated update for own 32-dim slab; publish packed h (nt stores) ----
    uint2v* pubS = pub + (size_t)((s & 1) * NGROUP + group) * 1536;
    const bool sb = (s < 12);
    if (t < 192) {
#pragma unroll
      for (int half = 0; half < 2; ++half) {
        int pos = t + half * 192;          // 0..383
        int c = pos >> 5, dl = pos & 31;
        int d = wgq * 32 + dl;
        const float* gr = &g_lds[c * GSTR];
        float g0 = gr[dl], g1 = gr[32 + dl], g2 = gr[64 + dl];
        float g3 = gr[96 + dl], g4 = gr[128 + dl], g5 = gr[160 + dl];
        if (sb && (c <= s)) {
          g0 += bias_l[dl]; g1 += bias_l[32 + dl]; g2 += bias_l[64 + dl];
          g3 += bias_l[96 + dl]; g4 += bias_l[128 + dl]; g5 += bias_l[160 + dl];
        }
        float ur = sigmoidf_(g0), orr = sigmoidf_(g1);
        float uc = sigmoidf_(g2), oc = sigmoidf_(g3);
        float ir = tanh_(g4), ic = tanh_(g5);
        float hr_old = bf2f(Ahi[c * ASTR + d]) + bf2f(Alo[c * ASTR + d]);
        float hc_old = bf2f(Ahi[c * ASTR + 128 + d]) + bf2f(Alo[c * ASTR + 128 + d]);
        float hr = tanh_((1.f - ur) * hr_old + ur * ir) * orr;
        float hc = tanh_((1.f - uc) * hc_old + uc * ic) * oc;
        uint2v v = {packbf(hr), packbf(hc)};
        __builtin_nontemporal_store(v, &pubS[c * 128 + d]);
      }
    }
    __syncthreads();  // drains all publish stores (vmcnt) wg-wide

    // ---- (4) release-bump flag; x prefetch for s+1 overlaps the poll ----
    if (t == 0) ATOMIC_ADD_REL(flag, 1u);
    if (s < 26 && t < 192) {
      int c = t >> 4, j8 = (t & 15) * 8;
      int r = (s + 1) - c;
      short8 vh = {0, 0, 0, 0, 0, 0, 0, 0}, vl = vh;
      if (r >= 0 && r < 16) {
        vh = *(const short8*)(hgh + (r * 12 + c) * Hdim + j8);
        vl = *(const short8*)(hgl + (r * 12 + c) * Hdim + j8);
      }
      *(short8*)&Ahi[c * ASTR + 256 + j8] = vh;
      *(short8*)&Alo[c * ASTR + 256 + j8] = vl;
    }
    if (t == 0) {
      const unsigned tgt = 4u * (s + 1);
      int guard = 0;
      while (ATOMIC_LD_RLX(flag) < tgt) {
        __builtin_amdgcn_s_sleep(1);
        if (++guard > (1 << 20)) break;  // valve (diagnostic)
      }
    }
    __syncthreads();

    // ---- (5) acquire (per-wave L1/L2 inv), then scatter all 4 slabs into A ----
    acq_sink |= ATOMIC_LD_ACQ(flag);
#pragma unroll
    for (int i = 0; i < 3; ++i) {
      int pidx = t + 256 * i;         // 0..767
      int c = pidx >> 6;
      int d = (pidx & 63) * 2;        // even
      uint4v u = *(const uint4v*)&pubS[c * 128 + d];
      unsigned rowhi = (u.x >> 16) | (u.z & 0xFFFF0000u);
      unsigned rowlo = (u.x & 0xFFFFu) | (u.z << 16);
      unsigned colhi = (u.y >> 16) | (u.w & 0xFFFF0000u);
      unsigned collo = (u.y & 0xFFFFu) | (u.w << 16);
      *(unsigned*)&Ahi[c * ASTR + d] = rowhi;
      *(unsigned*)&Alo[c * ASTR + d] = rowlo;
      int c2 = (c == 11) ? 0 : c + 1;  // roll: new h_col[c] feeds slice c+1
      *(unsigned*)&Ahi[c2 * ASTR + 128 + d] = colhi;
      *(unsigned*)&Alo[c2 * ASTR + 128 + d] = collo;
    }
    __syncthreads();
  }

  // ---- epilogue: h_row[11] at A[11][0:128); h_col_new[11] at A[0][128:256) ----
  if (t < 128) {
    float hr = bf2f(Ahi[11 * ASTR + t]) + bf2f(Alo[11 * ASTR + t]);
    float hc = bf2f(Ahi[0 * ASTR + 128 + t]) + bf2f(Alo[0 * ASTR + 128 + t]);
    red[t] = 0.5f * (hc * fc1_w[cls * Hdim + t] + hr * fc2_w[cls * Hdim + t]);
  }
  __syncthreads();
  if (wgq == 0 && t == 0) {
    float sum = 0.f;
    for (int i = 0; i < 128; ++i) sum += red[i];
    out[bn * 2 + cls] = sum + 0.5f * (fc1_b[cls] + fc2_b[cls]);
  }
  if (acq_sink == 0xFFFFFFFFu && t == 1) out[0] = -1e30f;  // keep acquires alive (never true)
}

extern "C" void kernel_launch(void* const* d_in, const int* in_sizes, int n_in,
                              void* d_out, int out_size, void* d_ws, size_t ws_size,
                              hipStream_t stream) {
  const float* x = (const float*)d_in[0];
  // d_in[1] = pad_mask: unused by the reference
  const float* fc3_w = (const float*)d_in[2];
  const float* fc3_b = (const float*)d_in[3];
  const float* fc4_w = (const float*)d_in[4];
  const float* fc4_b = (const float*)d_in[5];
  const float* W_enc = (const float*)d_in[6];
  const float* B_enc = (const float*)d_in[7];
  const float* fc1_w = (const float*)d_in[8];
  const float* fc1_b = (const float*)d_in[9];
  const float* fc2_w = (const float*)d_in[10];
  const float* fc2_b = (const float*)d_in[11];
  float* out = (float*)d_out;

  char* ws = (char*)d_ws;
  short* wfrag = (short*)ws;                     //  1,179,648 B
  short* hg_hi = (short*)(ws + 1179648);         //  3,145,728 B
  short* hg_lo = (short*)(ws + 4325376);         //  3,145,728 B
  uint2v* pub = (uint2v*)(ws + 7471104);         //  3,145,728 B (2-parity x 128 x 1536 x 8 B)
  unsigned* flags = (unsigned*)(ws + 10616832);  //      8,192 B

  hipMemsetAsync(flags, 0, 128 * 16 * sizeof(unsigned), stream);
  prep_w<<<dim3(2304), dim3(256), 0, stream>>>(W_enc, wfrag);
  frontend16<<<dim3(768), dim3(128), 0, stream>>>(x, fc3_w, fc3_b, fc4_w, fc4_b, hg_hi, hg_lo);
  witran<<<dim3(512), dim3(256), 0, stream>>>(hg_hi, hg_lo, wfrag, B_enc,
                                              fc1_w, fc1_b, fc2_w, fc2_b, pub, flags, out);
}

// Round 4
// 214.981 us; speedup vs baseline: 3.6167x; 3.6167x over previous
//
#include <hip/hip_runtime.h>

typedef short short8 __attribute__((ext_vector_type(8)));
typedef float f32x4 __attribute__((ext_vector_type(4)));
typedef unsigned long long ull;

constexpr int Hdim = 128;   // H
constexpr int Steps = 27;   // COL + ROW - 1
constexpr int Ndim = 768;   // 6H
constexpr int ASTR = 392;   // A-row stride in shorts (784 B); 2-way LDS aliasing = b128 floor
constexpr int GSTR = 389;   // g_lds row stride in floats (odd -> conflict-free)
constexpr int NGROUP = 128; // (cls, bn) pairs

__device__ __forceinline__ short f2bf(float f) {
  unsigned u = __float_as_uint(f);
  u += 0x7FFFu + ((u >> 16) & 1u);  // RNE
  return (short)(u >> 16);
}
__device__ __forceinline__ float bf2f(short s) {
  return __uint_as_float(((unsigned)(unsigned short)s) << 16);
}
__device__ __forceinline__ unsigned packbf(float v) {
  unsigned short hi = (unsigned short)f2bf(v);
  unsigned short lo = (unsigned short)f2bf(v - bf2f((short)hi));
  return ((unsigned)hi << 16) | (unsigned)lo;
}
__device__ __forceinline__ float sigmoidf_(float x) { return 1.0f / (1.0f + __expf(-x)); }
__device__ __forceinline__ float tanh_(float x) { return 1.0f - 2.0f / (__expf(2.0f * x) + 1.0f); }

#define ATOMIC_LD_RLX(p) __hip_atomic_load((p), __ATOMIC_RELAXED, __HIP_MEMORY_SCOPE_AGENT)
#define ATOMIC_ST_RLX(p, v) __hip_atomic_store((p), (v), __ATOMIC_RELAXED, __HIP_MEMORY_SCOPE_AGENT)
#define ATOMIC_ADD_RLX(p, v) __hip_atomic_fetch_add((p), (v), __ATOMIC_RELAXED, __HIP_MEMORY_SCOPE_AGENT)

// ---- kernel 1: W_enc (fp32) -> MFMA B-fragment bf16, 2-slab output permutation ----
// permuted col p = q*384 + gate*64 + dl  <->  original n = gate*128 + q*64 + dl  (q in {0,1})
// idx = ((cls*48 + pt)*12 + ks)*512 + lane*8 + j
__global__ void prep_w(const float* __restrict__ W_enc, short* __restrict__ wfrag) {
  int idx = blockIdx.x * 256 + threadIdx.x;
  if (idx >= 2 * 48 * 12 * 512) return;
  int j = idx & 7;
  int lane = (idx >> 3) & 63;
  int rest = idx >> 9;
  int ks = rest % 12;
  int tmp = rest / 12;
  int pt = tmp % 48;
  int cls = tmp / 48;
  int p = pt * 16 + (lane & 15);
  int q = p / 384, c_loc = p % 384;
  int gate = c_loc >> 6, dl = c_loc & 63;
  int n = gate * 128 + q * 64 + dl;
  int k = ks * 32 + (lane >> 4) * 8 + j;
  wfrag[idx] = f2bf(W_enc[(cls * Ndim + n) * 384 + k]);
}

// ---- kernel 2: front-end MLP, LDS-staged weights, 16 rows/block ----
constexpr int WBS = 66;  // wbuf stride (floats)
__global__ __launch_bounds__(128) void frontend16(
    const float* __restrict__ x, const float* __restrict__ fc3_w, const float* __restrict__ fc3_b,
    const float* __restrict__ fc4_w, const float* __restrict__ fc4_b,
    short* __restrict__ hg_hi, short* __restrict__ hg_lo) {
  const int t = threadIdx.x;
  const int row0 = blockIdx.x * 16;
  __shared__ float wbuf[128 * WBS];
  __shared__ float xs[16][64];
  __shared__ float h1[16][128];
  for (int f = t; f < 1024; f += 128) {
    int r = f >> 6, c = f & 63;
    xs[r][c] = x[(size_t)(row0 + r) * 64 + c];
  }
  for (int f = t; f < 8192; f += 128) {  // w3: [h][c]
    int h = f >> 6, c = f & 63;
    wbuf[h * WBS + c] = fc3_w[f];
  }
  const float b3 = fc3_b[t], b4 = fc4_b[t];
  __syncthreads();
  float a[16];
#pragma unroll
  for (int r = 0; r < 16; ++r) a[r] = b3;
#pragma unroll 4
  for (int c = 0; c < 64; c += 2) {
    float2 w = *(const float2*)&wbuf[t * WBS + c];
#pragma unroll
    for (int r = 0; r < 16; ++r) {
      float2 xv = *(const float2*)&xs[r][c];
      a[r] = fmaf(xv.x, w.x, a[r]);
      a[r] = fmaf(xv.y, w.y, a[r]);
    }
  }
  __syncthreads();
#pragma unroll
  for (int r = 0; r < 16; ++r) h1[r][t] = fmaxf(a[r], 0.f);
  float o[16];
#pragma unroll
  for (int r = 0; r < 16; ++r) o[r] = b4;
  for (int half = 0; half < 2; ++half) {
    for (int f = t; f < 8192; f += 128) {
      int h = f >> 6, j = f & 63;
      wbuf[h * WBS + j] = fc4_w[h * 128 + half * 64 + j];
    }
    __syncthreads();
#pragma unroll 4
    for (int j = 0; j < 64; j += 2) {
      float2 w = *(const float2*)&wbuf[t * WBS + j];
#pragma unroll
      for (int r = 0; r < 16; ++r) {
        float2 hv = *(const float2*)&h1[r][half * 64 + j];
        o[r] = fmaf(hv.x, w.x, o[r]);
        o[r] = fmaf(hv.y, w.y, o[r]);
      }
    }
    __syncthreads();
  }
#pragma unroll
  for (int r = 0; r < 16; ++r) {
    short hb = f2bf(o[r]);
    hg_hi[(size_t)(row0 + r) * 128 + t] = hb;
    hg_lo[(size_t)(row0 + r) * 128 + t] = f2bf(o[r] - bf2f(hb));
  }
}

// ---- kernel 3: 2-wg groups (512 thr); register weights; relaxed-atomic LLC h-exchange ----
__global__ __launch_bounds__(512, 2) void witran(
    const short* __restrict__ hg_hi, const short* __restrict__ hg_lo,
    const short* __restrict__ wfrag, const float* __restrict__ B_enc,
    const float* __restrict__ fc1_w, const float* __restrict__ fc1_b,
    const float* __restrict__ fc2_w, const float* __restrict__ fc2_b,
    ull* __restrict__ pub, unsigned* __restrict__ flags, float* __restrict__ out) {
  const int wgq = blockIdx.x >> 7;    // 0/1 : owns dims [wgq*64, wgq*64+64) of every gate
  const int group = blockIdx.x & 127; // (cls, bn)
  const int cls = group & 1;
  const int bn = group >> 1;
  const int t = threadIdx.x;          // 0..511
  const int lane = t & 63;
  const int wv = t >> 6;              // wave 0..7: local cols [wv*48, wv*48+48)
  const int arow = lane & 15;
  const int quad = lane >> 4;

  __shared__ __attribute__((aligned(16))) short Ahi[16 * ASTR];
  __shared__ __attribute__((aligned(16))) short Alo[16 * ASTR];
  __shared__ float g_lds[12 * GSTR];
  __shared__ float bias_l[384];
  __shared__ float red[128];

  for (int i = t; i < 16 * ASTR; i += 512) { Ahi[i] = 0; Alo[i] = 0; }
  if (t < 384) {  // own slab bias: c_loc = gate*64+dl -> n = gate*128 + wgq*64 + dl
    int gate = t >> 6, dl = t & 63;
    bias_l[t] = B_enc[cls * Ndim + gate * 128 + wgq * 64 + dl];
  }

  // persistent weight fragments: wave wv owns pt = wgq*24 + wv*3 + {0,1,2}
  short8 w0[12], w1[12], w2[12];
  {
    const short* wfc = wfrag + (size_t)cls * (48 * 12 * 512) + (size_t)lane * 8;
    const int ptb = wgq * 24 + wv * 3;
#pragma unroll
    for (int ks = 0; ks < 12; ++ks) w0[ks] = *(const short8*)(wfc + ((ptb + 0) * 12 + ks) * 512);
#pragma unroll
    for (int ks = 0; ks < 12; ++ks) w1[ks] = *(const short8*)(wfc + ((ptb + 1) * 12 + ks) * 512);
#pragma unroll
    for (int ks = 0; ks < 12; ++ks) w2[ks] = *(const short8*)(wfc + ((ptb + 2) * 12 + ks) * 512);
  }

  const short* hgh = hg_hi + (size_t)bn * 192 * Hdim;
  const short* hgl = hg_lo + (size_t)bn * 192 * Hdim;
  unsigned* flag = flags + group * 16;  // 64 B padded

  __syncthreads();

  // x segment for step 0 (A row c, k in [256,384))
  if (t < 192) {
    int c = t >> 4, j8 = (t & 15) * 8;
    short8 vh = {0, 0, 0, 0, 0, 0, 0, 0}, vl = vh;
    if (c == 0) {
      vh = *(const short8*)(hgh + j8);
      vl = *(const short8*)(hgl + j8);
    }
    *(short8*)&Ahi[c * ASTR + 256 + j8] = vh;
    *(short8*)&Alo[c * ASTR + 256 + j8] = vl;
  }
  __syncthreads();

  const int abase = arow * ASTR + quad * 8;

  for (int s = 0; s < Steps; ++s) {
    // ---- (1) GEMM: A (LDS, hi/lo bf16) x W (regs) -> own 384-col stripe ----
    f32x4 a0 = {0.f, 0.f, 0.f, 0.f}, a1 = a0, a2 = a0;
#pragma unroll
    for (int ks = 0; ks < 12; ++ks) {
      short8 ah = *(const short8*)&Ahi[abase + ks * 32];
      short8 al = *(const short8*)&Alo[abase + ks * 32];
      a0 = __builtin_amdgcn_mfma_f32_16x16x32_bf16(ah, w0[ks], a0, 0, 0, 0);
      a1 = __builtin_amdgcn_mfma_f32_16x16x32_bf16(ah, w1[ks], a1, 0, 0, 0);
      a2 = __builtin_amdgcn_mfma_f32_16x16x32_bf16(ah, w2[ks], a2, 0, 0, 0);
      a0 = __builtin_amdgcn_mfma_f32_16x16x32_bf16(al, w0[ks], a0, 0, 0, 0);
      a1 = __builtin_amdgcn_mfma_f32_16x16x32_bf16(al, w1[ks], a1, 0, 0, 0);
      a2 = __builtin_amdgcn_mfma_f32_16x16x32_bf16(al, w2[ks], a2, 0, 0, 0);
    }
    if (quad < 3) {
      int c0 = wv * 48 + arow;
#pragma unroll
      for (int r = 0; r < 4; ++r) {
        int row = quad * 4 + r;
        g_lds[row * GSTR + c0 + 0] = a0[r];
        g_lds[row * GSTR + c0 + 16] = a1[r];
        g_lds[row * GSTR + c0 + 32] = a2[r];
      }
    }
    __syncthreads();  // #1: spill visible; all waves done reading A

    // ---- (3a) read old h for own slab into regs (kills col-roll WAR race) ----
    float hro[2], hco[2];
#pragma unroll
    for (int i2 = 0; i2 < 2; ++i2) {
      int pos = t + i2 * 512;  // 0..1023 -> use < 768
      if (pos < 768) {
        int c = pos >> 6, dl = pos & 63, d = wgq * 64 + dl;
        hro[i2] = bf2f(Ahi[c * ASTR + d]) + bf2f(Alo[c * ASTR + d]);
        hco[i2] = bf2f(Ahi[c * ASTR + 128 + d]) + bf2f(Alo[c * ASTR + 128 + d]);
      }
    }
    __syncthreads();  // #2: old values captured before overwrite

    // ---- (3b) gated update for own slab: write A locally + publish to LLC ----
    ull* pubS = pub + (size_t)((s & 1) * NGROUP + group) * 1536;
    const bool sb = (s < 12);
#pragma unroll
    for (int i2 = 0; i2 < 2; ++i2) {
      int pos = t + i2 * 512;
      if (pos < 768) {
        int c = pos >> 6, dl = pos & 63, d = wgq * 64 + dl;
        const float* gr = &g_lds[c * GSTR];
        float g0 = gr[dl], g1 = gr[64 + dl], g2 = gr[128 + dl];
        float g3 = gr[192 + dl], g4 = gr[256 + dl], g5 = gr[320 + dl];
        if (sb && (c <= s)) {
          g0 += bias_l[dl]; g1 += bias_l[64 + dl]; g2 += bias_l[128 + dl];
          g3 += bias_l[192 + dl]; g4 += bias_l[256 + dl]; g5 += bias_l[320 + dl];
        }
        float ur = sigmoidf_(g0), orr = sigmoidf_(g1);
        float uc = sigmoidf_(g2), oc = sigmoidf_(g3);
        float ir = tanh_(g4), ic = tanh_(g5);
        float hr = tanh_((1.f - ur) * hro[i2] + ur * ir) * orr;
        float hc = tanh_((1.f - uc) * hco[i2] + uc * ic) * oc;
        unsigned rp = packbf(hr), cp = packbf(hc);
        Ahi[c * ASTR + d] = (short)(rp >> 16);
        Alo[c * ASTR + d] = (short)(rp & 0xFFFFu);
        int c2 = (c == 11) ? 0 : c + 1;  // roll: new h_col[c] feeds slice c+1
        Ahi[c2 * ASTR + 128 + d] = (short)(cp >> 16);
        Alo[c2 * ASTR + 128 + d] = (short)(cp & 0xFFFFu);
        ATOMIC_ST_RLX(&pubS[c * 128 + d], (ull)rp | ((ull)cp << 32));
      }
    }
    __syncthreads();  // #3: drains vmcnt -> publish globally visible before bump

    // ---- (4) bump flag; x prefetch for s+1 overlaps the poll ----
    if (t == 0) ATOMIC_ADD_RLX(flag, 1u);
    if (s < 26 && t < 192) {
      int c = t >> 4, j8 = (t & 15) * 8;
      int r = (s + 1) - c;
      short8 vh = {0, 0, 0, 0, 0, 0, 0, 0}, vl = vh;
      if (r >= 0 && r < 16) {
        vh = *(const short8*)(hgh + (r * 12 + c) * Hdim + j8);
        vl = *(const short8*)(hgl + (r * 12 + c) * Hdim + j8);
      }
      *(short8*)&Ahi[c * ASTR + 256 + j8] = vh;
      *(short8*)&Alo[c * ASTR + 256 + j8] = vl;
    }
    if (t == 0) {
      const unsigned tgt = 2u * (s + 1);
      int guard = 0;
      while (ATOMIC_LD_RLX(flag) < tgt) {
        __builtin_amdgcn_s_sleep(1);
        if (++guard > (1 << 20)) break;  // valve (diagnostic)
      }
    }
    __syncthreads();  // #4: partner's publish confirmed

    // ---- (5) fetch partner slab from LLC, scatter into A ----
    {
      const int rq = 1 - wgq;
      for (int e = t; e < 768; e += 512) {
        int c = e >> 6, dl = e & 63, d = rq * 64 + dl;
        ull v = ATOMIC_LD_RLX(&pubS[c * 128 + d]);
        unsigned rp = (unsigned)v, cp = (unsigned)(v >> 32);
        Ahi[c * ASTR + d] = (short)(rp >> 16);
        Alo[c * ASTR + d] = (short)(rp & 0xFFFFu);
        int c2 = (c == 11) ? 0 : c + 1;
        Ahi[c2 * ASTR + 128 + d] = (short)(cp >> 16);
        Alo[c2 * ASTR + 128 + d] = (short)(cp & 0xFFFFu);
      }
    }
    __syncthreads();  // #5: A complete for next GEMM
  }

  // ---- epilogue: h_row[11] at A[11][0:128); h_col_new[11] at A[0][128:256) ----
  if (t < 128) {
    float hr = bf2f(Ahi[11 * ASTR + t]) + bf2f(Alo[11 * ASTR + t]);
    float hc = bf2f(Ahi[0 * ASTR + 128 + t]) + bf2f(Alo[0 * ASTR + 128 + t]);
    red[t] = 0.5f * (hc * fc1_w[cls * Hdim + t] + hr * fc2_w[cls * Hdim + t]);
  }
  __syncthreads();
  if (wgq == 0 && t == 0) {
    float sum = 0.f;
    for (int i = 0; i < 128; ++i) sum += red[i];
    out[bn * 2 + cls] = sum + 0.5f * (fc1_b[cls] + fc2_b[cls]);
  }
}

extern "C" void kernel_launch(void* const* d_in, const int* in_sizes, int n_in,
                              void* d_out, int out_size, void* d_ws, size_t ws_size,
                              hipStream_t stream) {
  const float* x = (const float*)d_in[0];
  // d_in[1] = pad_mask: unused by the reference
  const float* fc3_w = (const float*)d_in[2];
  const float* fc3_b = (const float*)d_in[3];
  const float* fc4_w = (const float*)d_in[4];
  const float* fc4_b = (const float*)d_in[5];
  const float* W_enc = (const float*)d_in[6];
  const float* B_enc = (const float*)d_in[7];
  const float* fc1_w = (const float*)d_in[8];
  const float* fc1_b = (const float*)d_in[9];
  const float* fc2_w = (const float*)d_in[10];
  const float* fc2_b = (const float*)d_in[11];
  float* out = (float*)d_out;

  char* ws = (char*)d_ws;
  short* wfrag = (short*)ws;                     //  1,179,648 B
  short* hg_hi = (short*)(ws + 1179648);         //  3,145,728 B
  short* hg_lo = (short*)(ws + 4325376);         //  3,145,728 B
  ull* pub = (ull*)(ws + 7471104);               //  3,145,728 B (2-parity x 128 x 1536 x 8 B)
  unsigned* flags = (unsigned*)(ws + 10616832);  //      8,192 B

  hipMemsetAsync(flags, 0, 128 * 16 * sizeof(unsigned), stream);
  prep_w<<<dim3(2304), dim3(256), 0, stream>>>(W_enc, wfrag);
  frontend16<<<dim3(768), dim3(128), 0, stream>>>(x, fc3_w, fc3_b, fc4_w, fc4_b, hg_hi, hg_lo);
  witran<<<dim3(256), dim3(512), 0, stream>>>(hg_hi, hg_lo, wfrag, B_enc,
                                              fc1_w, fc1_b, fc2_w, fc2_b, pub, flags, out);
}